// Round 5
// baseline (4871.822 us; speedup 1.0000x reference)
//
#include <hip/hip_runtime.h>
#include <hip/hip_bf16.h>

// WeightedGNN forward, MI355X. Round 10: block-per-batch, zero cross-block sync.
// Round 9 (same structure) FAILED correctness because the LDS XOR swizzle used a
// 528-B row stride: XOR on byte bits 4-6 is only row-local if the row stride is
// a multiple of 128 B. hswz(1,248)==hswz(2,8) collided (row 2 clobbered row 1).
// Fix: stride 512 B ( (row<<9) + 2c ) ^ ((row&7)<<4) -> bijective, and the
// 16-row ds_read_b128 A-frag reads spread across all 32 banks (<=2-way, free).
// Structure (verified line-by-line vs passing round-3 layouts): the entire
// 64-step recurrence of batch b runs inside ONE 1024-thread block; h lives in
// LDS; P is produced and consumed chunk-by-chunk (GEMM1 -> in-reg LN -> LDS
// B-frags -> GEMM2 accumulate); weights stream from per-XCD L2. Plain launches.
// B=16, L=64, D=256, NRELS=8.

#define DD 256
#define LLEN 64
#define BBAT 16
#define NROWS 1024   // B*L

typedef __attribute__((ext_vector_type(8))) short short8;          // 8 bf16
typedef __attribute__((ext_vector_type(4))) unsigned short us4;    // 4 bf16
typedef __attribute__((ext_vector_type(4))) float f32x4;

__device__ inline unsigned short f2bf(float x) {
    unsigned int u = __float_as_uint(x);
    unsigned int r = (u + 0x7fffu + ((u >> 16) & 1u)) >> 16;
    return (unsigned short)r;
}

// byte address into a [64][256] u16 LDS tile (512-B row stride), XOR-swizzled.
// Stride is a multiple of 128 B => XOR on bits 4-6 is row-local => bijective.
__device__ inline int hswz(int row, int colu16) {
    return ((row << 9) + (colu16 << 1)) ^ ((row & 7) << 4);
}

// ---------------- fused one-time prep: cvtW | cvtA | cvtWo | inproj | setup ---
__global__ __launch_bounds__(256) void k_prep(
    const int* __restrict__ tokens, const float* __restrict__ A,
    const float* __restrict__ emb,
    const float* __restrict__ Wp, const float* __restrict__ Wi,
    const float* __restrict__ bi, const float* __restrict__ Wo,
    unsigned short* __restrict__ Wf, unsigned short* __restrict__ Af,
    unsigned short* __restrict__ Wof,
    float* __restrict__ shiftb, float* __restrict__ scaleb, float* __restrict__ projx,
    int* __restrict__ lengths)
{
    __shared__ float xs[8][DD];
    const int tid = threadIdx.x;
    const int bid = blockIdx.x;

    if (bid < 256) {
        // ---- W_proj [256][2048] fp32 -> bf16 B-fragment layout ----
        int t = bid * 256 + tid;   // 65536
        int l = t & 63; int rest = t >> 6;
        int tk = rest & 7; rest >>= 3;
        int tn = rest & 15; int hh = rest >> 4;
        int kbase = tk * 32 + (l >> 4) * 8;
        int n = hh * 256 + tn * 16 + (l & 15);
        union { short8 v; unsigned short u[8]; } pk;
#pragma unroll
        for (int j = 0; j < 8; ++j) pk.u[j] = f2bf(Wp[(kbase + j) * 2048 + n]);
        *(short8*)(Wf + (long)t * 8) = pk.v;
    } else if (bid < 512) {
        // ---- A_rels -> bf16 A-fragment layout, K-order k = h*64 + i ----
        int t = (bid - 256) * 256 + tid;   // 65536
        int lane = t & 63;
        int tk = (t >> 6) & 15;
        int jg = (t >> 10) & 3;
        int b  = t >> 12;
        int j = jg * 16 + (lane & 15);
        int kbase = tk * 32 + (lane >> 4) * 8;
        int h  = kbase >> 6;
        int i0 = kbase & 63;
        union { short8 v; unsigned short u[8]; } pk;
#pragma unroll
        for (int jj = 0; jj < 8; ++jj)
            pk.u[jj] = f2bf(A[((long)(b * 64 + i0 + jj) * 64 + j) * 8 + h]);
        *(short8*)(Af + (long)t * 8) = pk.v;
    } else if (bid < 544) {
        // ---- W_out [256][256] fp32 -> bf16 B-fragment layout ----
        int t = (bid - 512) * 256 + tid;   // 8192
        int lane = t & 63;
        int tk = (t >> 6) & 7;
        int nt = t >> 9;
        int kbase = tk * 32 + (lane >> 4) * 8;
        int n = nt * 16 + (lane & 15);
        union { short8 v; unsigned short u[8]; } pk;
#pragma unroll
        for (int j = 0; j < 8; ++j) pk.u[j] = f2bf(Wo[(kbase + j) * 256 + n]);
        *(short8*)(Wof + (long)t * 8) = pk.v;
    } else if (bid < 928) {
        // ---- in_proj: gather emb + [1024x256]@[256x768], 384 blocks ----
        int lb = bid - 544;
        int rowx = lb & 127, nc = lb >> 7;    // nc: 0=shift 1=scale 2=projx
        const int row0 = rowx * 8;
        for (int r = 0; r < 8; ++r) {
            int row = row0 + r;
            int b = row >> 6, l = row & 63;
            int tok = tokens[l * BBAT + b];
            xs[r][tid] = emb[(long)tok * DD + tid];
        }
        __syncthreads();
        const int col = nc * 256 + tid;
        float a[8];
#pragma unroll
        for (int r = 0; r < 8; ++r) a[r] = 0.f;
#pragma unroll 4
        for (int k = 0; k < DD; ++k) {
            float wv = Wi[k * 768 + col];
#pragma unroll
            for (int r = 0; r < 8; ++r) a[r] = fmaf(xs[r][k], wv, a[r]);
        }
        const float bia = bi[col];
        float* dst = (nc == 0) ? shiftb : (nc == 1) ? scaleb : projx;
#pragma unroll
        for (int r = 0; r < 8; ++r) dst[(row0 + r) * DD + tid] = a[r] + bia;
    } else {
        // ---- lengths[b] ----
        if (tid < BBAT) {
            int c = 0;
            for (int l = 0; l < LLEN; ++l) c += (tokens[l * BBAT + tid] != 0) ? 1 : 0;
            lengths[tid] = c;
        }
    }
}

// ---------------- whole recurrence, one block per batch ----------------------
// 16 waves: wave (ig = w>>2, wv = w&3). Per chunk hh: GEMM1 (h rows ig*16..+16,
// chunk cols wv*64..+64, K=256) -> in-reg LN -> P_chunk B-frags in scr ->
// GEMM2 partial (j rows ig*16..+16, d cols wv*64..+64, K=64) accumulate.
// Epilogue1: shrink+projx+LN+gate+relu -> hsb (scr, swizzled). GEMM3: hsb@Wof.
// Epilogue2: tanh+mask -> h (LDS, swizzled) [+ h_out fp32 last iter].
__global__ __launch_bounds__(1024, 1) void k_loop(
    const unsigned short* __restrict__ Af,     // [16 b][4 jg][16 tk][64][8]
    const float* __restrict__ projx,
    const float* __restrict__ shiftb,
    const float* __restrict__ scaleb,
    const unsigned short* __restrict__ Wf,     // [8 hh][16 tn][8 tk][64][8]
    const float* __restrict__ bp,              // [2048]
    const unsigned short* __restrict__ Wof,    // [16 nt][8 tk][64][8]
    const float* __restrict__ bout,
    const int* __restrict__ lengths,
    float* __restrict__ h_out)                 // [1024][256] fp32 (last iter)
{
    __shared__ __align__(16) unsigned char h_raw[64 * 512];    // 32 KB: h (bf16, swizzled)
    __shared__ __align__(16) unsigned char scr_raw[64 * 512];  // 32 KB: P-frags / hsb
    __shared__ float part[4][64][2];                            // 2 KB
    __shared__ float bp_lds[2048];                              // 8 KB

    const int t = threadIdx.x;
    const int w = t >> 6, lane = t & 63;
    const int b = blockIdx.x;
    const int ig = w >> 2, wv = w & 3;
    const int cl = lane & 15;
    const int r4 = (lane >> 4) * 4;
    const int i0row = ig * 16 + r4;            // this thread's 4-row base (0..63)
    const int len_b = lengths[b];

    // init: zero h, stage bp, hoist bout
    for (int i = t; i < 64 * 256; i += 1024) ((unsigned short*)h_raw)[i] = 0;
    for (int i = t; i < 2048; i += 1024) bp_lds[i] = bp[i];
    float bov[4];
#pragma unroll
    for (int tn = 0; tn < 4; ++tn) bov[tn] = bout[wv * 64 + tn * 16 + cl];
    __syncthreads();

    for (int it = 0; it < 64; ++it) {
        // ---- hoist h A-fragments for this iteration (rows ig*16..+16) ----
        short8 a8[8];
#pragma unroll
        for (int tk = 0; tk < 8; ++tk)
            a8[tk] = *(const short8*)(h_raw + hswz(ig * 16 + cl, tk * 32 + (lane >> 4) * 8));

        f32x4 acc2[4];
#pragma unroll
        for (int tn = 0; tn < 4; ++tn) acc2[tn] = (f32x4){0.f, 0.f, 0.f, 0.f};

        for (int hh = 0; hh < 8; ++hh) {
            // ======== GEMM1: C1 = h @ Wp_chunk (wave: 32 MFMA, K=256) ========
            f32x4 acc1[4];
#pragma unroll
            for (int tn = 0; tn < 4; ++tn) acc1[tn] = (f32x4){0.f, 0.f, 0.f, 0.f};
            const unsigned short* wB = Wf + (long)(((hh * 16 + wv * 4) * 8) * 64 + lane) * 8;
#pragma unroll
            for (int tk = 0; tk < 8; ++tk)
#pragma unroll
                for (int tn = 0; tn < 4; ++tn) {
                    short8 bb = *(const short8*)(wB + (tn * 8 + tk) * 512);
                    acc1[tn] = __builtin_amdgcn_mfma_f32_16x16x32_bf16(a8[tk], bb, acc1[tn], 0, 0, 0);
                }
            // ======== per-(row,chunk) LayerNorm, in-register ========
            float vals[4][4];   // [tn][r]
#pragma unroll
            for (int tn = 0; tn < 4; ++tn) {
                float bpv = bp_lds[hh * 256 + wv * 64 + tn * 16 + cl];
#pragma unroll
                for (int r = 0; r < 4; ++r) vals[tn][r] = acc1[tn][r] + bpv;
            }
            float s_[4], ss_[4];
#pragma unroll
            for (int r = 0; r < 4; ++r) {
                s_[r] = (vals[0][r] + vals[1][r]) + (vals[2][r] + vals[3][r]);
                float q0 = vals[0][r] * vals[0][r];
                q0 = fmaf(vals[1][r], vals[1][r], q0);
                q0 = fmaf(vals[2][r], vals[2][r], q0);
                ss_[r] = fmaf(vals[3][r], vals[3][r], q0);
            }
#pragma unroll
            for (int m = 1; m <= 8; m <<= 1)
#pragma unroll
                for (int r = 0; r < 4; ++r) {
                    s_[r]  += __shfl_xor(s_[r], m);
                    ss_[r] += __shfl_xor(ss_[r], m);
                }
            if (cl == 0)
#pragma unroll
                for (int r = 0; r < 4; ++r) {
                    part[wv][i0row + r][0] = s_[r];
                    part[wv][i0row + r][1] = ss_[r];
                }
            __syncthreads();
            float mean_[4], rstd_[4];
#pragma unroll
            for (int r = 0; r < 4; ++r) {
                int row = i0row + r;
                float s  = (part[0][row][0] + part[1][row][0]) + (part[2][row][0] + part[3][row][0]);
                float ss = (part[0][row][1] + part[1][row][1]) + (part[2][row][1] + part[3][row][1]);
                mean_[r] = s * (1.f / 256.f);
                float var = ss * (1.f / 256.f) - mean_[r] * mean_[r];
                rstd_[r] = rsqrtf(var + 1e-5f);
            }
            // ---- write P_chunk as GEMM2 B-fragments into scr (linear) ----
            // element (i, d) -> frag[tk2=i>>5][nt=d>>4][lane2][j=i&7],
            // lane2 = ((i&31)>>3)<<4 | (d&15); r=0..3 contiguous in j.
            {
                const int tk2 = i0row >> 5;
                const int lane2 = (((i0row & 31) >> 3) << 4) | cl;
                const int j0 = i0row & 7;       // 0 or 4
#pragma unroll
                for (int tn = 0; tn < 4; ++tn) {
                    us4 pk;
#pragma unroll
                    for (int r = 0; r < 4; ++r)
                        pk[r] = f2bf((vals[tn][r] - mean_[r]) * rstd_[r]);
                    *(us4*)(scr_raw + (((tk2 * 16 + wv * 4 + tn) * 64 + lane2) * 8 + j0) * 2) = pk;
                }
            }
            __syncthreads();
            // ======== GEMM2 partial: acc2 += A_chunk @ P_chunk (8 MFMA) ======
            const unsigned short* ab = Af + ((((long)b * 4 + ig) * 16 + hh * 2) * 64 + lane) * 8;
#pragma unroll
            for (int tkk = 0; tkk < 2; ++tkk) {
                short8 a = *(const short8*)(ab + tkk * 512);
#pragma unroll
                for (int tn = 0; tn < 4; ++tn) {
                    short8 pbf = *(const short8*)(scr_raw + ((tkk * 16 + wv * 4 + tn) * 64 + lane) * 16);
                    acc2[tn] = __builtin_amdgcn_mfma_f32_16x16x32_bf16(a, pbf, acc2[tn], 0, 0, 0);
                }
            }
            __syncthreads();
        } // hh

        // ======== epilogue 1: shrink + projx + LN + gate + relu -> hsb =======
        const int rowg0 = b * 64 + i0row;
        float tv[4][4];
#pragma unroll
        for (int tn = 0; tn < 4; ++tn) {
            int colg = wv * 64 + tn * 16 + cl;
#pragma unroll
            for (int r = 0; r < 4; ++r) {
                float lin = acc2[tn][r];
                float shr = lin - tanhf(lin);
                tv[tn][r] = projx[(rowg0 + r) * DD + colg] + shr;
            }
        }
        {
            float s_[4], ss_[4];
#pragma unroll
            for (int r = 0; r < 4; ++r) {
                s_[r] = (tv[0][r] + tv[1][r]) + (tv[2][r] + tv[3][r]);
                float q0 = tv[0][r] * tv[0][r];
                q0 = fmaf(tv[1][r], tv[1][r], q0);
                q0 = fmaf(tv[2][r], tv[2][r], q0);
                ss_[r] = fmaf(tv[3][r], tv[3][r], q0);
            }
#pragma unroll
            for (int m = 1; m <= 8; m <<= 1)
#pragma unroll
                for (int r = 0; r < 4; ++r) {
                    s_[r]  += __shfl_xor(s_[r], m);
                    ss_[r] += __shfl_xor(ss_[r], m);
                }
            if (cl == 0)
#pragma unroll
                for (int r = 0; r < 4; ++r) {
                    part[wv][i0row + r][0] = s_[r];
                    part[wv][i0row + r][1] = ss_[r];
                }
        }
        __syncthreads();
        {
            float mean_[4], rstd_[4];
#pragma unroll
            for (int r = 0; r < 4; ++r) {
                int row = i0row + r;
                float s  = (part[0][row][0] + part[1][row][0]) + (part[2][row][0] + part[3][row][0]);
                float ss = (part[0][row][1] + part[1][row][1]) + (part[2][row][1] + part[3][row][1]);
                mean_[r] = s * (1.f / 256.f);
                float var = ss * (1.f / 256.f) - mean_[r] * mean_[r];
                rstd_[r] = rsqrtf(var + 1e-5f);
            }
#pragma unroll
            for (int tn = 0; tn < 4; ++tn) {
                int colg = wv * 64 + tn * 16 + cl;
#pragma unroll
                for (int r = 0; r < 4; ++r) {
                    float nv = (tv[tn][r] - mean_[r]) * rstd_[r];
                    float hv = fmaf(shiftb[(rowg0 + r) * DD + colg], nv,
                                    scaleb[(rowg0 + r) * DD + colg]);
                    *(unsigned short*)(scr_raw + hswz(i0row + r, colg)) = f2bf(fmaxf(hv, 0.f));
                }
            }
        }
        __syncthreads();

        // ======== GEMM3: y = hsb @ W_out (wave: 32 MFMA, K=256) ==============
        f32x4 acc3[4];
#pragma unroll
        for (int tn = 0; tn < 4; ++tn) acc3[tn] = (f32x4){0.f, 0.f, 0.f, 0.f};
        short8 a3[8];
#pragma unroll
        for (int tk = 0; tk < 8; ++tk)
            a3[tk] = *(const short8*)(scr_raw + hswz(ig * 16 + cl, tk * 32 + (lane >> 4) * 8));
        const unsigned short* wo = Wof + (long)(((wv * 4) * 8) * 64 + lane) * 8;
#pragma unroll
        for (int tk = 0; tk < 8; ++tk)
#pragma unroll
            for (int tn = 0; tn < 4; ++tn) {
                short8 bb = *(const short8*)(wo + (tn * 8 + tk) * 512);
                acc3[tn] = __builtin_amdgcn_mfma_f32_16x16x32_bf16(a3[tk], bb, acc3[tn], 0, 0, 0);
            }

        // ======== epilogue 2: tanh + mask -> h (LDS) [+ fp32 out last iter] ==
        const bool maskz = (64 - it) > len_b;
#pragma unroll
        for (int tn = 0; tn < 4; ++tn) {
            int colg = wv * 64 + tn * 16 + cl;
#pragma unroll
            for (int r = 0; r < 4; ++r) {
                float y = tanhf(acc3[tn][r] + bov[tn]);
                float ym = maskz ? 0.f : y;
                *(unsigned short*)(h_raw + hswz(i0row + r, colg)) = f2bf(ym);
                if (it == 63) h_out[(rowg0 + r) * DD + colg] = ym;
            }
        }
        __syncthreads();
    } // it
}

// ---------------- final: out[b,d] = sum_i h[b,i,d] * root[b,i] ----------------
__global__ __launch_bounds__(256) void k_final(
    const float* __restrict__ h_buf, const float* __restrict__ root,
    float* __restrict__ out)
{
    const int t = threadIdx.x;
    const int b = blockIdx.x;
    float acc = 0.f;
    for (int i = 0; i < LLEN; ++i)
        acc = fmaf(h_buf[(b * 64 + i) * DD + t], root[b * 64 + i], acc);
    out[b * DD + t] = acc;
}

extern "C" void kernel_launch(void* const* d_in, const int* in_sizes, int n_in,
                              void* d_out, int out_size, void* d_ws, size_t ws_size,
                              hipStream_t stream)
{
    const int*   tokens = (const int*)  d_in[0];
    const float* A      = (const float*)d_in[1];
    const float* root   = (const float*)d_in[2];
    const float* emb    = (const float*)d_in[3];
    const float* Wp     = (const float*)d_in[4];
    const float* bp     = (const float*)d_in[5];
    const float* Wi     = (const float*)d_in[6];
    const float* bi     = (const float*)d_in[7];
    const float* Wo     = (const float*)d_in[8];
    const float* bo     = (const float*)d_in[9];
    float* out = (float*)d_out;

    char* ws = (char*)d_ws;
    int*   lengths = (int*)(ws + 0);
    float* shiftb  = (float*)(ws + 1024);
    float* scaleb  = shiftb + NROWS * DD;
    float* projx   = scaleb + NROWS * DD;
    float* h_out   = projx  + NROWS * DD;                          // 1 MB fp32
    unsigned short* Wf  = (unsigned short*)(h_out + NROWS * DD);   // 1 MB
    unsigned short* Af  = Wf + 524288;                             // 1 MB
    unsigned short* Wof = Af + 524288;                             // 128 KB

    k_prep<<<929, 256, 0, stream>>>(tokens, A, emb, Wp, Wi, bi, Wo,
                                    Wf, Af, Wof, shiftb, scaleb, projx, lengths);
    k_loop<<<16, 1024, 0, stream>>>(Af, projx, shiftb, scaleb, Wf, bp,
                                    Wof, bo, lengths, h_out);
    k_final<<<16, 256, 0, stream>>>(h_out, root, out);
}

// Round 7
// 4350.985 us; speedup vs baseline: 1.1197x; 1.1197x over previous
//
#include <hip/hip_runtime.h>
#include <hip/hip_bf16.h>

// WeightedGNN forward, MI355X. Round 12: block-per-batch persistent recurrence.
// Round 11 FAILED correctness: Af->LDS staging copied only 2048 of 4096 short8s
// (64 KB needs 4 x 16 B per thread at 1024 threads) -> GEMM2 for ig>=2 read
// uninitialized LDS (absmax 0.30). Fixed here (4-store loop). Also replaced the
// raw v_exp_f32 inline asm with __builtin_amdgcn_exp2f so the compiler handles
// the TRANS-op hazard/scheduling. Everything else identical to round 11:
//  - Wf/Wof B-frags: 3-deep prefetch rotation (covers L2 latency under MFMA)
//  - Af pinned in LDS (64 KB, once) -> GEMM2 fully LDS-local
//  - 19 barriers/iter (post-GEMM2 sync subsumed by next chunk's part-sync)
//  - LN partials vectorized: part2[64][8], b128 reads
//  - tanh = 1 - 2*rcp(exp2(2x*log2e)+1)  (~1e-6 abs err, bf16-invisible)
//  - projx/shift/scale pre-reordered -> 4x b128 loads per use site
// B=16, L=64, D=256, NRELS=8.

#define DD 256
#define LLEN 64
#define BBAT 16
#define NROWS 1024   // B*L

typedef __attribute__((ext_vector_type(8))) short short8;          // 8 bf16
typedef __attribute__((ext_vector_type(4))) unsigned short us4;    // 4 bf16
typedef __attribute__((ext_vector_type(4))) float f32x4;

__device__ inline unsigned short f2bf(float x) {
    unsigned int u = __float_as_uint(x);
    unsigned int r = (u + 0x7fffu + ((u >> 16) & 1u)) >> 16;
    return (unsigned short)r;
}

// fast tanh: 1 - 2/(2^(2x*log2e)+1). Exact at +-inf; ~1e-6 abs err (output
// feeds bf16, granularity ~4e-3). exp2 builtin -> v_exp_f32 with proper hazards.
__device__ inline float ftanh(float x) {
    float e = __builtin_amdgcn_exp2f(x * 2.8853900817779268f);
    return 1.0f - 2.0f * __builtin_amdgcn_rcpf(e + 1.0f);
}

// byte address into a [64][256] u16 LDS tile (512-B row stride), XOR-swizzled.
// Row stride multiple of 128 B => XOR on bits 4-6 is row-local => bijective.
__device__ inline int hswz(int row, int colu16) {
    return ((row << 9) + (colu16 << 1)) ^ ((row & 7) << 4);
}

// ---------------- fused one-time prep: cvtW | cvtA | cvtWo | inproj | setup ---
__global__ __launch_bounds__(256) void k_prep(
    const int* __restrict__ tokens, const float* __restrict__ A,
    const float* __restrict__ emb,
    const float* __restrict__ Wp, const float* __restrict__ Wi,
    const float* __restrict__ bi, const float* __restrict__ Wo,
    unsigned short* __restrict__ Wf, unsigned short* __restrict__ Af,
    unsigned short* __restrict__ Wof,
    float* __restrict__ shift2, float* __restrict__ scale2, float* __restrict__ projx2,
    int* __restrict__ lengths)
{
    __shared__ float xs[8][DD];
    const int tid = threadIdx.x;
    const int bid = blockIdx.x;

    if (bid < 256) {
        // ---- W_proj [256][2048] fp32 -> bf16 B-fragment layout ----
        int t = bid * 256 + tid;   // 65536
        int l = t & 63; int rest = t >> 6;
        int tk = rest & 7; rest >>= 3;
        int tn = rest & 15; int hh = rest >> 4;
        int kbase = tk * 32 + (l >> 4) * 8;
        int n = hh * 256 + tn * 16 + (l & 15);
        union { short8 v; unsigned short u[8]; } pk;
#pragma unroll
        for (int j = 0; j < 8; ++j) pk.u[j] = f2bf(Wp[(kbase + j) * 2048 + n]);
        *(short8*)(Wf + (long)t * 8) = pk.v;
    } else if (bid < 512) {
        // ---- A_rels -> bf16 A-fragment layout, K-order k = h*64 + i ----
        int t = (bid - 256) * 256 + tid;   // 65536
        int lane = t & 63;
        int tk = (t >> 6) & 15;
        int jg = (t >> 10) & 3;
        int b  = t >> 12;
        int j = jg * 16 + (lane & 15);
        int kbase = tk * 32 + (lane >> 4) * 8;
        int h  = kbase >> 6;
        int i0 = kbase & 63;
        union { short8 v; unsigned short u[8]; } pk;
#pragma unroll
        for (int jj = 0; jj < 8; ++jj)
            pk.u[jj] = f2bf(A[((long)(b * 64 + i0 + jj) * 64 + j) * 8 + h]);
        *(short8*)(Af + (long)t * 8) = pk.v;
    } else if (bid < 544) {
        // ---- W_out [256][256] fp32 -> bf16 B-fragment layout ----
        int t = (bid - 512) * 256 + tid;   // 8192
        int lane = t & 63;
        int tk = (t >> 6) & 7;
        int nt = t >> 9;
        int kbase = tk * 32 + (lane >> 4) * 8;
        int n = nt * 16 + (lane & 15);
        union { short8 v; unsigned short u[8]; } pk;
#pragma unroll
        for (int j = 0; j < 8; ++j) pk.u[j] = f2bf(Wo[(kbase + j) * 256 + n]);
        *(short8*)(Wof + (long)t * 8) = pk.v;
    } else if (bid < 928) {
        // ---- in_proj: gather emb + [1024x256]@[256x768] ----
        // Output REORDERED for k_loop: thread (b, w=ig*4+wv, lane=lhi*16+cl)
        // owns 16 contiguous f32 at ((b*16+w)*64+lane)*16, inner idx r*4+tn,
        // value = orig[b*64 + ig*16 + lhi*4 + r][wv*64 + tn*16 + cl].
        int lb = bid - 544;
        int rowx = lb & 127, nc = lb >> 7;    // nc: 0=shift 1=scale 2=projx
        const int row0 = rowx * 8;
        for (int r = 0; r < 8; ++r) {
            int row = row0 + r;
            int b = row >> 6, l = row & 63;
            int tok = tokens[l * BBAT + b];
            xs[r][tid] = emb[(long)tok * DD + tid];
        }
        __syncthreads();
        const int col = nc * 256 + tid;
        float a[8];
#pragma unroll
        for (int r = 0; r < 8; ++r) a[r] = 0.f;
#pragma unroll 4
        for (int k = 0; k < DD; ++k) {
            float wv_ = Wi[k * 768 + col];
#pragma unroll
            for (int r = 0; r < 8; ++r) a[r] = fmaf(xs[r][k], wv_, a[r]);
        }
        const float bia = bi[col];
        float* dst = (nc == 0) ? shift2 : (nc == 1) ? scale2 : projx2;
        const int wv = tid >> 6, tn = (tid >> 4) & 3, cl = tid & 15;
#pragma unroll
        for (int rr = 0; rr < 8; ++rr) {
            int row = row0 + rr;
            int b_ = row >> 6, lrow = row & 63;
            int ig = lrow >> 4, r16 = lrow & 15;
            int lhi = r16 >> 2, r_ = r16 & 3;
            long idx = (((long)(b_ * 16 + ig * 4 + wv) * 64) + lhi * 16 + cl) * 16 + r_ * 4 + tn;
            dst[idx] = a[rr] + bia;
        }
    } else {
        // ---- lengths[b] ----
        if (tid < BBAT) {
            int c = 0;
            for (int l = 0; l < LLEN; ++l) c += (tokens[l * BBAT + tid] != 0) ? 1 : 0;
            lengths[tid] = c;
        }
    }
}

// ---------------- whole recurrence, one block per batch ----------------------
// 16 waves: wave (ig = w>>2, wv = w&3). Per chunk hh: GEMM1 (h rows ig*16..+16,
// chunk cols wv*64..+64, K=256, Wf 3-deep prefetch) -> in-reg LN -> P_chunk
// B-frags in scr -> GEMM2 partial (K=64, Af from LDS) accumulate.
// Epilogue1: shrink+projx+LN+gate+relu -> hsb (scr, swizzled). GEMM3: hsb@Wof.
// Epilogue2: tanh+mask -> h (LDS, swizzled) [+ h_out fp32 last iter].
__global__ __launch_bounds__(1024, 1) void k_loop(
    const unsigned short* __restrict__ Af,     // [16 b][4 ig][16 tk][64][8]
    const float* __restrict__ projx2,          // reordered, see k_prep
    const float* __restrict__ shift2,
    const float* __restrict__ scale2,
    const unsigned short* __restrict__ Wf,     // [8 hh][16 tn][8 tk][64][8]
    const float* __restrict__ bp,              // [2048]
    const unsigned short* __restrict__ Wof,    // [16 nt][8 tk][64][8]
    const float* __restrict__ bout,
    const int* __restrict__ lengths,
    float* __restrict__ h_out)                 // [1024][256] fp32 (last iter)
{
    __shared__ __align__(16) unsigned char h_raw[32768];     // h (bf16, swizzled)
    __shared__ __align__(16) unsigned char scr_raw[32768];   // P-frags / hsb
    __shared__ float part2[64][8];                           // LN partials (vec)
    __shared__ float bp_lds[2048];
    __shared__ __align__(16) unsigned short af_lds[32768];   // Af[b], 64 KB

    const int t = threadIdx.x;
    const int w = t >> 6, lane = t & 63;
    const int b = blockIdx.x;
    const int ig = w >> 2, wv = w & 3;
    const int cl = lane & 15;
    const int lhi = lane >> 4;
    const int r4 = lhi * 4;
    const int i0row = ig * 16 + r4;            // this thread's 4-row base (0..63)
    const int len_b = lengths[b];

    // init: zero h, stage bp, stage Af[b] (64 KB = 4096 short8, 4 per thread)
    for (int i = t; i < 64 * 256; i += 1024) ((unsigned short*)h_raw)[i] = 0;
    for (int i = t; i < 2048; i += 1024) bp_lds[i] = bp[i];
    {
        const short8* src = (const short8*)(Af + (long)b * 32768);
        short8* dst = (short8*)af_lds;
#pragma unroll
        for (int i = 0; i < 4; ++i) dst[t + i * 1024] = src[t + i * 1024];
    }
    float bov[4];
#pragma unroll
    for (int tn = 0; tn < 4; ++tn) bov[tn] = bout[wv * 64 + tn * 16 + cl];
    __syncthreads();

    const float* pxb = projx2 + ((long)(b * 16 + w) * 64 + lane) * 16;
    const float* shb = shift2 + ((long)(b * 16 + w) * 64 + lane) * 16;
    const float* scb = scale2 + ((long)(b * 16 + w) * 64 + lane) * 16;

    for (int it = 0; it < 64; ++it) {
        f32x4 acc2[4];
#pragma unroll
        for (int tn = 0; tn < 4; ++tn) acc2[tn] = (f32x4){0.f, 0.f, 0.f, 0.f};

        for (int hh = 0; hh < 8; ++hh) {
            // ======== GEMM1: C1 = h @ Wp_chunk (32 MFMA, K=256) ========
            // Wf loads 3-deep prefetched; h A-frags per-tk from LDS.
            const unsigned short* wB = Wf + ((long)((hh * 16 + wv * 4) * 8) * 64 + lane) * 8;
            f32x4 acc1[4];
#pragma unroll
            for (int tn = 0; tn < 4; ++tn) acc1[tn] = (f32x4){0.f, 0.f, 0.f, 0.f};
            short8 bb[3][4];
#pragma unroll
            for (int tn = 0; tn < 4; ++tn) bb[0][tn] = *(const short8*)(wB + (tn * 8 + 0) * 512);
#pragma unroll
            for (int tn = 0; tn < 4; ++tn) bb[1][tn] = *(const short8*)(wB + (tn * 8 + 1) * 512);
#pragma unroll
            for (int tk = 0; tk < 8; ++tk) {
                if (tk < 6) {
#pragma unroll
                    for (int tn = 0; tn < 4; ++tn)
                        bb[(tk + 2) % 3][tn] = *(const short8*)(wB + (tn * 8 + tk + 2) * 512);
                }
                short8 av = *(const short8*)(h_raw + hswz(ig * 16 + cl, tk * 32 + lhi * 8));
#pragma unroll
                for (int tn = 0; tn < 4; ++tn)
                    acc1[tn] = __builtin_amdgcn_mfma_f32_16x16x32_bf16(av, bb[tk % 3][tn], acc1[tn], 0, 0, 0);
            }
            // ======== per-(row,chunk) LayerNorm, in-register ========
            float vals[4][4];   // [tn][r]
#pragma unroll
            for (int tn = 0; tn < 4; ++tn) {
                float bpv = bp_lds[hh * 256 + wv * 64 + tn * 16 + cl];
#pragma unroll
                for (int r = 0; r < 4; ++r) vals[tn][r] = acc1[tn][r] + bpv;
            }
            float s_[4], ss_[4];
#pragma unroll
            for (int r = 0; r < 4; ++r) {
                s_[r] = (vals[0][r] + vals[1][r]) + (vals[2][r] + vals[3][r]);
                float q0 = vals[0][r] * vals[0][r];
                q0 = fmaf(vals[1][r], vals[1][r], q0);
                q0 = fmaf(vals[2][r], vals[2][r], q0);
                ss_[r] = fmaf(vals[3][r], vals[3][r], q0);
            }
#pragma unroll
            for (int m = 1; m <= 8; m <<= 1)
#pragma unroll
                for (int r = 0; r < 4; ++r) {
                    s_[r]  += __shfl_xor(s_[r], m);
                    ss_[r] += __shfl_xor(ss_[r], m);
                }
            if (cl == 0)
#pragma unroll
                for (int r = 0; r < 4; ++r) {
                    float2 p2 = {s_[r], ss_[r]};
                    *(float2*)&part2[i0row + r][wv * 2] = p2;
                }
            __syncthreads();   // sync_a: part complete; also orders scr reuse
            float mean_[4], rstd_[4];
#pragma unroll
            for (int r = 0; r < 4; ++r) {
                f32x4 lo = *(const f32x4*)&part2[i0row + r][0];
                f32x4 hi = *(const f32x4*)&part2[i0row + r][4];
                float s  = (lo[0] + lo[2]) + (hi[0] + hi[2]);
                float ss = (lo[1] + lo[3]) + (hi[1] + hi[3]);
                mean_[r] = s * (1.f / 256.f);
                float var = ss * (1.f / 256.f) - mean_[r] * mean_[r];
                rstd_[r] = rsqrtf(var + 1e-5f);
            }
            // ---- write P_chunk as GEMM2 B-fragments into scr (linear) ----
            {
                const int tk2 = i0row >> 5;
                const int lane2 = (((i0row & 31) >> 3) << 4) | cl;
                const int j0 = i0row & 7;       // 0 or 4
#pragma unroll
                for (int tn = 0; tn < 4; ++tn) {
                    us4 pk;
#pragma unroll
                    for (int r = 0; r < 4; ++r)
                        pk[r] = f2bf((vals[tn][r] - mean_[r]) * rstd_[r]);
                    *(us4*)(scr_raw + (((tk2 * 16 + wv * 4 + tn) * 64 + lane2) * 8 + j0) * 2) = pk;
                }
            }
            __syncthreads();   // sync_b: P_chunk visible
            // ======== GEMM2 partial: acc2 += A_chunk @ P_chunk (8 MFMA) ======
#pragma unroll
            for (int tkk = 0; tkk < 2; ++tkk) {
                short8 a = *(const short8*)(af_lds + ((ig * 16 + hh * 2 + tkk) * 64 + lane) * 8);
#pragma unroll
                for (int tn = 0; tn < 4; ++tn) {
                    short8 pbf = *(const short8*)(scr_raw + ((tkk * 16 + wv * 4 + tn) * 64 + lane) * 16);
                    acc2[tn] = __builtin_amdgcn_mfma_f32_16x16x32_bf16(a, pbf, acc2[tn], 0, 0, 0);
                }
            }
            // no sync here: next chunk's sync_a orders scr reuse (all waves must
            // finish these reads before any wave's next scr write, which happens
            // after sync_a)
        } // hh

        // ======== epilogue 1: shrink + projx + LN + gate + relu -> hsb =======
        const int rowg0 = b * 64 + i0row;
        f32x4 px[4];
#pragma unroll
        for (int r = 0; r < 4; ++r) px[r] = *(const f32x4*)(pxb + r * 4);
        float tv[4][4];
#pragma unroll
        for (int tn = 0; tn < 4; ++tn)
#pragma unroll
            for (int r = 0; r < 4; ++r) {
                float lin = acc2[tn][r];
                float shr = lin - ftanh(lin);
                tv[tn][r] = px[r][tn] + shr;
            }
        {
            float s_[4], ss_[4];
#pragma unroll
            for (int r = 0; r < 4; ++r) {
                s_[r] = (tv[0][r] + tv[1][r]) + (tv[2][r] + tv[3][r]);
                float q0 = tv[0][r] * tv[0][r];
                q0 = fmaf(tv[1][r], tv[1][r], q0);
                q0 = fmaf(tv[2][r], tv[2][r], q0);
                ss_[r] = fmaf(tv[3][r], tv[3][r], q0);
            }
#pragma unroll
            for (int m = 1; m <= 8; m <<= 1)
#pragma unroll
                for (int r = 0; r < 4; ++r) {
                    s_[r]  += __shfl_xor(s_[r], m);
                    ss_[r] += __shfl_xor(ss_[r], m);
                }
            if (cl == 0)
#pragma unroll
                for (int r = 0; r < 4; ++r) {
                    float2 p2 = {s_[r], ss_[r]};
                    *(float2*)&part2[i0row + r][wv * 2] = p2;
                }
        }
        __syncthreads();   // sync_E1
        {
            f32x4 sh[4], sc[4];
#pragma unroll
            for (int r = 0; r < 4; ++r) {
                sh[r] = *(const f32x4*)(shb + r * 4);
                sc[r] = *(const f32x4*)(scb + r * 4);
            }
            float mean_[4], rstd_[4];
#pragma unroll
            for (int r = 0; r < 4; ++r) {
                f32x4 lo = *(const f32x4*)&part2[i0row + r][0];
                f32x4 hi = *(const f32x4*)&part2[i0row + r][4];
                float s  = (lo[0] + lo[2]) + (hi[0] + hi[2]);
                float ss = (lo[1] + lo[3]) + (hi[1] + hi[3]);
                mean_[r] = s * (1.f / 256.f);
                float var = ss * (1.f / 256.f) - mean_[r] * mean_[r];
                rstd_[r] = rsqrtf(var + 1e-5f);
            }
#pragma unroll
            for (int tn = 0; tn < 4; ++tn) {
                int colg = wv * 64 + tn * 16 + cl;
#pragma unroll
                for (int r = 0; r < 4; ++r) {
                    float nv = (tv[tn][r] - mean_[r]) * rstd_[r];
                    float hv = fmaf(sh[r][tn], nv, sc[r][tn]);
                    *(unsigned short*)(scr_raw + hswz(i0row + r, colg)) = f2bf(fmaxf(hv, 0.f));
                }
            }
        }
        __syncthreads();   // sync_E2: hsb complete

        // ======== GEMM3: y = hsb @ W_out (32 MFMA, K=256, Wof prefetched) ====
        const unsigned short* wo = Wof + (long)(((wv * 4) * 8) * 64 + lane) * 8;
        f32x4 acc3[4];
#pragma unroll
        for (int tn = 0; tn < 4; ++tn) acc3[tn] = (f32x4){0.f, 0.f, 0.f, 0.f};
        {
            short8 bb[3][4];
#pragma unroll
            for (int tn = 0; tn < 4; ++tn) bb[0][tn] = *(const short8*)(wo + (tn * 8 + 0) * 512);
#pragma unroll
            for (int tn = 0; tn < 4; ++tn) bb[1][tn] = *(const short8*)(wo + (tn * 8 + 1) * 512);
#pragma unroll
            for (int tk = 0; tk < 8; ++tk) {
                if (tk < 6) {
#pragma unroll
                    for (int tn = 0; tn < 4; ++tn)
                        bb[(tk + 2) % 3][tn] = *(const short8*)(wo + (tn * 8 + tk + 2) * 512);
                }
                short8 av = *(const short8*)(scr_raw + hswz(ig * 16 + cl, tk * 32 + lhi * 8));
#pragma unroll
                for (int tn = 0; tn < 4; ++tn)
                    acc3[tn] = __builtin_amdgcn_mfma_f32_16x16x32_bf16(av, bb[tk % 3][tn], acc3[tn], 0, 0, 0);
            }
        }

        // ======== epilogue 2: tanh + mask -> h (LDS) [+ fp32 out last iter] ==
        const bool maskz = (64 - it) > len_b;
#pragma unroll
        for (int tn = 0; tn < 4; ++tn) {
            int colg = wv * 64 + tn * 16 + cl;
#pragma unroll
            for (int r = 0; r < 4; ++r) {
                float y = ftanh(acc3[tn][r] + bov[tn]);
                float ym = maskz ? 0.f : y;
                *(unsigned short*)(h_raw + hswz(i0row + r, colg)) = f2bf(ym);
                if (it == 63) h_out[(rowg0 + r) * DD + colg] = ym;
            }
        }
        __syncthreads();   // sync_E3: h ready for next iteration
    } // it
}

// ---------------- final: out[b,d] = sum_i h[b,i,d] * root[b,i] ----------------
__global__ __launch_bounds__(256) void k_final(
    const float* __restrict__ h_buf, const float* __restrict__ root,
    float* __restrict__ out)
{
    const int t = threadIdx.x;
    const int b = blockIdx.x;
    float acc = 0.f;
    for (int i = 0; i < LLEN; ++i)
        acc = fmaf(h_buf[(b * 64 + i) * DD + t], root[b * 64 + i], acc);
    out[b * DD + t] = acc;
}

extern "C" void kernel_launch(void* const* d_in, const int* in_sizes, int n_in,
                              void* d_out, int out_size, void* d_ws, size_t ws_size,
                              hipStream_t stream)
{
    const int*   tokens = (const int*)  d_in[0];
    const float* A      = (const float*)d_in[1];
    const float* root   = (const float*)d_in[2];
    const float* emb    = (const float*)d_in[3];
    const float* Wp     = (const float*)d_in[4];
    const float* bp     = (const float*)d_in[5];
    const float* Wi     = (const float*)d_in[6];
    const float* bi     = (const float*)d_in[7];
    const float* Wo     = (const float*)d_in[8];
    const float* bo     = (const float*)d_in[9];
    float* out = (float*)d_out;

    char* ws = (char*)d_ws;
    int*   lengths = (int*)(ws + 0);
    float* shift2  = (float*)(ws + 1024);
    float* scale2  = shift2 + NROWS * DD;
    float* projx2  = scale2 + NROWS * DD;
    float* h_out   = projx2 + NROWS * DD;                          // 1 MB fp32
    unsigned short* Wf  = (unsigned short*)(h_out + NROWS * DD);   // 1 MB
    unsigned short* Af  = Wf + 524288;                             // 1 MB
    unsigned short* Wof = Af + 524288;                             // 128 KB

    k_prep<<<929, 256, 0, stream>>>(tokens, A, emb, Wp, Wi, bi, Wo,
                                    Wf, Af, Wof, shift2, scale2, projx2, lengths);
    k_loop<<<16, 1024, 0, stream>>>(Af, projx2, shift2, scale2, Wf, bp,
                                    Wof, bo, lengths, h_out);
    k_final<<<16, 256, 0, stream>>>(h_out, root, out);
}

// Round 8
// 3794.397 us; speedup vs baseline: 1.2840x; 1.1467x over previous
//
#include <hip/hip_runtime.h>
#include <hip/hip_bf16.h>

// WeightedGNN forward, MI355X. Round 13: block-per-batch + LDS-staged weights.
// r10/r12 counters: VGPR=64 -> compiler demoted the Wf reg-prefetch to JIT L2
// loads; each (ig,wv) wave re-reads its wv-column of Wf => 4 MB/iter/CU of
// L2->CU traffic (~27 us at ~150 GB/s per-CU port) + exposed latency = the
// 68 us/iter wall. Fix: Wf staged once per chunk through LDS via
// __builtin_amdgcn_global_load_lds (async, wave-uniform dest + lane*16B),
// double-buffered at 32 KB (2-tk) granularity -> L2 traffic 1 MB/iter, latency
// hidden by the barrier-pipelined stage(tp+1) || MFMA(tp) overlap. Af returns
// to global reads (256 KB/iter, cheap) freeing 64 KB LDS for the two buffers.
// Wof staged the same way (2 x 64 KB halves) for GEMM3. Math identical to the
// twice-passing r10/r12 kernels. B=16, L=64, D=256, NRELS=8.

#define DD 256
#define LLEN 64
#define BBAT 16
#define NROWS 1024   // B*L

typedef __attribute__((ext_vector_type(8))) short short8;          // 8 bf16
typedef __attribute__((ext_vector_type(4))) unsigned short us4;    // 4 bf16
typedef __attribute__((ext_vector_type(4))) float f32x4;

__device__ inline unsigned short f2bf(float x) {
    unsigned int u = __float_as_uint(x);
    unsigned int r = (u + 0x7fffu + ((u >> 16) & 1u)) >> 16;
    return (unsigned short)r;
}

// fast tanh: 1 - 2/(2^(2x*log2e)+1). ~1e-6 abs err (output feeds bf16).
__device__ inline float ftanh(float x) {
    float e = __builtin_amdgcn_exp2f(x * 2.8853900817779268f);
    return 1.0f - 2.0f * __builtin_amdgcn_rcpf(e + 1.0f);
}

// byte address into a [64][256] u16 LDS tile (512-B row stride), XOR-swizzled.
__device__ inline int hswz(int row, int colu16) {
    return ((row << 9) + (colu16 << 1)) ^ ((row & 7) << 4);
}

// async global->LDS, 16 B per lane; dest = wave-uniform base + lane*16.
__device__ inline void gload_lds16(const unsigned short* g, unsigned short* l) {
    __builtin_amdgcn_global_load_lds(
        (const __attribute__((address_space(1))) unsigned int*)(g),
        (__attribute__((address_space(3))) unsigned int*)(l),
        16, 0, 0);
}

// stage one 32 KB half-chunk of Wf (tk pair tp) into buf.
// wave w stages (tn = w>>1 and w>>1+8, tkk = w&1): 2 x 16 B per lane.
__device__ inline void stage_wf(const unsigned short* __restrict__ Wf,
                                int hh, int tp, unsigned short* buf,
                                int w, int lane) {
    int tn1 = w >> 1, tkk = w & 1;
    int tk = tp * 2 + tkk;
    const unsigned short* g1 = Wf + (((hh * 16 + tn1) * 8 + tk) * 64 + lane) * 8;
    gload_lds16(g1,          buf + (unsigned)w * 512);
    gload_lds16(g1 + 32768,  buf + (unsigned)(w + 16) * 512);   // tn1+8: +8*8*512
}

// stage one 64 KB half of Wof (tk h*4..h*4+3) into the full wf region.
__device__ inline void stage_wof(const unsigned short* __restrict__ Wof,
                                 int h, unsigned short* wfl, int w, int lane) {
    int nt0 = w >> 2, tkh = w & 3;
#pragma unroll
    for (int k = 0; k < 4; ++k) {
        const unsigned short* g =
            Wof + ((((nt0 + k * 4) * 8) + h * 4 + tkh) * 64 + lane) * 8;
        gload_lds16(g, wfl + (unsigned)w * 512 + (unsigned)k * 8192);
    }
}

// ---------------- fused one-time prep: cvtW | cvtA | cvtWo | inproj | setup ---
__global__ __launch_bounds__(256) void k_prep(
    const int* __restrict__ tokens, const float* __restrict__ A,
    const float* __restrict__ emb,
    const float* __restrict__ Wp, const float* __restrict__ Wi,
    const float* __restrict__ bi, const float* __restrict__ Wo,
    unsigned short* __restrict__ Wf, unsigned short* __restrict__ Af,
    unsigned short* __restrict__ Wof,
    float* __restrict__ shift2, float* __restrict__ scale2, float* __restrict__ projx2,
    int* __restrict__ lengths)
{
    __shared__ float xs[8][DD];
    const int tid = threadIdx.x;
    const int bid = blockIdx.x;

    if (bid < 256) {
        // ---- W_proj [256][2048] fp32 -> bf16 B-fragment layout ----
        int t = bid * 256 + tid;   // 65536
        int l = t & 63; int rest = t >> 6;
        int tk = rest & 7; rest >>= 3;
        int tn = rest & 15; int hh = rest >> 4;
        int kbase = tk * 32 + (l >> 4) * 8;
        int n = hh * 256 + tn * 16 + (l & 15);
        union { short8 v; unsigned short u[8]; } pk;
#pragma unroll
        for (int j = 0; j < 8; ++j) pk.u[j] = f2bf(Wp[(kbase + j) * 2048 + n]);
        *(short8*)(Wf + (long)t * 8) = pk.v;
    } else if (bid < 512) {
        // ---- A_rels -> bf16 A-fragment layout, K-order k = h*64 + i ----
        int t = (bid - 256) * 256 + tid;   // 65536
        int lane = t & 63;
        int tk = (t >> 6) & 15;
        int jg = (t >> 10) & 3;
        int b  = t >> 12;
        int j = jg * 16 + (lane & 15);
        int kbase = tk * 32 + (lane >> 4) * 8;
        int h  = kbase >> 6;
        int i0 = kbase & 63;
        union { short8 v; unsigned short u[8]; } pk;
#pragma unroll
        for (int jj = 0; jj < 8; ++jj)
            pk.u[jj] = f2bf(A[((long)(b * 64 + i0 + jj) * 64 + j) * 8 + h]);
        *(short8*)(Af + (long)t * 8) = pk.v;
    } else if (bid < 544) {
        // ---- W_out [256][256] fp32 -> bf16 B-fragment layout ----
        int t = (bid - 512) * 256 + tid;   // 8192
        int lane = t & 63;
        int tk = (t >> 6) & 7;
        int nt = t >> 9;
        int kbase = tk * 32 + (lane >> 4) * 8;
        int n = nt * 16 + (lane & 15);
        union { short8 v; unsigned short u[8]; } pk;
#pragma unroll
        for (int j = 0; j < 8; ++j) pk.u[j] = f2bf(Wo[(kbase + j) * 256 + n]);
        *(short8*)(Wof + (long)t * 8) = pk.v;
    } else if (bid < 928) {
        // ---- in_proj: gather emb + [1024x256]@[256x768], reordered output ----
        int lb = bid - 544;
        int rowx = lb & 127, nc = lb >> 7;    // nc: 0=shift 1=scale 2=projx
        const int row0 = rowx * 8;
        for (int r = 0; r < 8; ++r) {
            int row = row0 + r;
            int b = row >> 6, l = row & 63;
            int tok = tokens[l * BBAT + b];
            xs[r][tid] = emb[(long)tok * DD + tid];
        }
        __syncthreads();
        const int col = nc * 256 + tid;
        float a[8];
#pragma unroll
        for (int r = 0; r < 8; ++r) a[r] = 0.f;
#pragma unroll 4
        for (int k = 0; k < DD; ++k) {
            float wv_ = Wi[k * 768 + col];
#pragma unroll
            for (int r = 0; r < 8; ++r) a[r] = fmaf(xs[r][k], wv_, a[r]);
        }
        const float bia = bi[col];
        float* dst = (nc == 0) ? shift2 : (nc == 1) ? scale2 : projx2;
        const int wv = tid >> 6, tn = (tid >> 4) & 3, cl = tid & 15;
#pragma unroll
        for (int rr = 0; rr < 8; ++rr) {
            int row = row0 + rr;
            int b_ = row >> 6, lrow = row & 63;
            int ig = lrow >> 4, r16 = lrow & 15;
            int lhi = r16 >> 2, r_ = r16 & 3;
            long idx = (((long)(b_ * 16 + ig * 4 + wv) * 64) + lhi * 16 + cl) * 16 + r_ * 4 + tn;
            dst[idx] = a[rr] + bia;
        }
    } else {
        // ---- lengths[b] ----
        if (tid < BBAT) {
            int c = 0;
            for (int l = 0; l < LLEN; ++l) c += (tokens[l * BBAT + tid] != 0) ? 1 : 0;
            lengths[tid] = c;
        }
    }
}

// ---------------- whole recurrence, one block per batch ----------------------
__global__ __launch_bounds__(1024, 1) void k_loop(
    const unsigned short* __restrict__ Af,     // [16 b][4 ig][16 tk][64][8]
    const float* __restrict__ projx2,          // reordered, see k_prep
    const float* __restrict__ shift2,
    const float* __restrict__ scale2,
    const unsigned short* __restrict__ Wf,     // [8 hh][16 tn][8 tk][64][8]
    const float* __restrict__ bp,              // [2048]
    const unsigned short* __restrict__ Wof,    // [16 nt][8 tk][64][8]
    const float* __restrict__ bout,
    const int* __restrict__ lengths,
    float* __restrict__ h_out)                 // [1024][256] fp32 (last iter)
{
    __shared__ __align__(16) unsigned char h_raw[32768];     // h (bf16, swizzled)
    __shared__ __align__(16) unsigned char scr_raw[32768];   // P-frags / hsb
    __shared__ __align__(16) unsigned short wf_lds[32768];   // 64 KB: 2x32KB stage bufs
    __shared__ float part2[64][8];                           // LN partials (vec)
    __shared__ float bp_lds[2048];

    const int t = threadIdx.x;
    const int w = t >> 6, lane = t & 63;
    const int b = blockIdx.x;
    const int ig = w >> 2, wv = w & 3;
    const int cl = lane & 15;
    const int lhi = lane >> 4;
    const int r4 = lhi * 4;
    const int i0row = ig * 16 + r4;
    const int len_b = lengths[b];

    for (int i = t; i < 64 * 256; i += 1024) ((unsigned short*)h_raw)[i] = 0;
    for (int i = t; i < 2048; i += 1024) bp_lds[i] = bp[i];
    float bov[4];
#pragma unroll
    for (int tn = 0; tn < 4; ++tn) bov[tn] = bout[wv * 64 + tn * 16 + cl];
    __syncthreads();

    const float* pxb = projx2 + ((long)(b * 16 + w) * 64 + lane) * 16;
    const float* shb = shift2 + ((long)(b * 16 + w) * 64 + lane) * 16;
    const float* scb = scale2 + ((long)(b * 16 + w) * 64 + lane) * 16;

    stage_wf(Wf, 0, 0, wf_lds, w, lane);   // prologue: chunk 0, tk-pair 0 -> buf0

    for (int it = 0; it < 64; ++it) {
        // ---- hoist h A-fragments (rows ig*16..+16) ----
        short8 a8[8];
#pragma unroll
        for (int tk = 0; tk < 8; ++tk)
            a8[tk] = *(const short8*)(h_raw + hswz(ig * 16 + cl, tk * 32 + lhi * 8));

        f32x4 acc2[4];
#pragma unroll
        for (int tn = 0; tn < 4; ++tn) acc2[tn] = (f32x4){0.f, 0.f, 0.f, 0.f};

        for (int hh = 0; hh < 8; ++hh) {
            // Af prefetch for GEMM2 (drained by first barrier, used after sync_b)
            const unsigned short* ab = Af + ((((long)b * 4 + ig) * 16 + hh * 2) * 64 + lane) * 8;
            short8 af0 = *(const short8*)ab;
            short8 af1 = *(const short8*)(ab + 512);

            // ======== GEMM1: pipelined stage || MFMA over 4 tk-pairs ========
            f32x4 acc1[4];
#pragma unroll
            for (int tn = 0; tn < 4; ++tn) acc1[tn] = (f32x4){0.f, 0.f, 0.f, 0.f};
#pragma unroll
            for (int tp = 0; tp < 4; ++tp) {
                __syncthreads();   // publish stage(hh,tp); retire reads of other buf
                if (tp < 3)      stage_wf(Wf, hh, tp + 1, wf_lds + ((tp + 1) & 1) * 16384, w, lane);
                else if (hh < 7) stage_wf(Wf, hh + 1, 0, wf_lds, w, lane);
                const unsigned short* cur = wf_lds + (tp & 1) * 16384;
#pragma unroll
                for (int tkk = 0; tkk < 2; ++tkk) {
                    short8 av = a8[tp * 2 + tkk];
#pragma unroll
                    for (int tn = 0; tn < 4; ++tn) {
                        short8 bbv = *(const short8*)(cur + ((wv * 8 + tn * 2 + tkk) * 64 + lane) * 8);
                        acc1[tn] = __builtin_amdgcn_mfma_f32_16x16x32_bf16(av, bbv, acc1[tn], 0, 0, 0);
                    }
                }
            }
            // ======== per-(row,chunk) LayerNorm, in-register ========
            float vals[4][4];   // [tn][r]
#pragma unroll
            for (int tn = 0; tn < 4; ++tn) {
                float bpv = bp_lds[hh * 256 + wv * 64 + tn * 16 + cl];
#pragma unroll
                for (int r = 0; r < 4; ++r) vals[tn][r] = acc1[tn][r] + bpv;
            }
            float s_[4], ss_[4];
#pragma unroll
            for (int r = 0; r < 4; ++r) {
                s_[r] = (vals[0][r] + vals[1][r]) + (vals[2][r] + vals[3][r]);
                float q0 = vals[0][r] * vals[0][r];
                q0 = fmaf(vals[1][r], vals[1][r], q0);
                q0 = fmaf(vals[2][r], vals[2][r], q0);
                ss_[r] = fmaf(vals[3][r], vals[3][r], q0);
            }
#pragma unroll
            for (int m = 1; m <= 8; m <<= 1)
#pragma unroll
                for (int r = 0; r < 4; ++r) {
                    s_[r]  += __shfl_xor(s_[r], m);
                    ss_[r] += __shfl_xor(ss_[r], m);
                }
            if (cl == 0)
#pragma unroll
                for (int r = 0; r < 4; ++r) {
                    float2 p2 = {s_[r], ss_[r]};
                    *(float2*)&part2[i0row + r][wv * 2] = p2;
                }
            __syncthreads();   // sync_a
            if (hh == 7) stage_wof(Wof, 0, wf_lds, w, lane);   // wf bufs free now
            float mean_[4], rstd_[4];
#pragma unroll
            for (int r = 0; r < 4; ++r) {
                f32x4 lo = *(const f32x4*)&part2[i0row + r][0];
                f32x4 hi = *(const f32x4*)&part2[i0row + r][4];
                float s  = (lo[0] + lo[2]) + (hi[0] + hi[2]);
                float ss = (lo[1] + lo[3]) + (hi[1] + hi[3]);
                mean_[r] = s * (1.f / 256.f);
                float var = ss * (1.f / 256.f) - mean_[r] * mean_[r];
                rstd_[r] = rsqrtf(var + 1e-5f);
            }
            // ---- write P_chunk as GEMM2 B-fragments into scr ----
            {
                const int tk2 = i0row >> 5;
                const int lane2 = (((i0row & 31) >> 3) << 4) | cl;
                const int j0 = i0row & 7;
#pragma unroll
                for (int tn = 0; tn < 4; ++tn) {
                    us4 pk;
#pragma unroll
                    for (int r = 0; r < 4; ++r)
                        pk[r] = f2bf((vals[tn][r] - mean_[r]) * rstd_[r]);
                    *(us4*)(scr_raw + (((tk2 * 16 + wv * 4 + tn) * 64 + lane2) * 8 + j0) * 2) = pk;
                }
            }
            __syncthreads();   // sync_b: P_chunk visible
            // ======== GEMM2 partial: acc2 += A_chunk @ P_chunk ========
#pragma unroll
            for (int tkk = 0; tkk < 2; ++tkk) {
                short8 a = (tkk == 0) ? af0 : af1;
#pragma unroll
                for (int tn = 0; tn < 4; ++tn) {
                    short8 pbf = *(const short8*)(scr_raw + ((tkk * 16 + wv * 4 + tn) * 64 + lane) * 16);
                    acc2[tn] = __builtin_amdgcn_mfma_f32_16x16x32_bf16(a, pbf, acc2[tn], 0, 0, 0);
                }
            }
            // no sync: next chunk's first barrier orders scr reuse
        } // hh

        // ======== epilogue 1: shrink + projx + LN + gate + relu -> hsb =======
        const int rowg0 = b * 64 + i0row;
        f32x4 px[4];
#pragma unroll
        for (int r = 0; r < 4; ++r) px[r] = *(const f32x4*)(pxb + r * 4);
        float tv[4][4];
#pragma unroll
        for (int tn = 0; tn < 4; ++tn)
#pragma unroll
            for (int r = 0; r < 4; ++r) {
                float lin = acc2[tn][r];
                float shr = lin - ftanh(lin);
                tv[tn][r] = px[r][tn] + shr;
            }
        {
            float s_[4], ss_[4];
#pragma unroll
            for (int r = 0; r < 4; ++r) {
                s_[r] = (tv[0][r] + tv[1][r]) + (tv[2][r] + tv[3][r]);
                float q0 = tv[0][r] * tv[0][r];
                q0 = fmaf(tv[1][r], tv[1][r], q0);
                q0 = fmaf(tv[2][r], tv[2][r], q0);
                ss_[r] = fmaf(tv[3][r], tv[3][r], q0);
            }
#pragma unroll
            for (int m = 1; m <= 8; m <<= 1)
#pragma unroll
                for (int r = 0; r < 4; ++r) {
                    s_[r]  += __shfl_xor(s_[r], m);
                    ss_[r] += __shfl_xor(ss_[r], m);
                }
            if (cl == 0)
#pragma unroll
                for (int r = 0; r < 4; ++r) {
                    float2 p2 = {s_[r], ss_[r]};
                    *(float2*)&part2[i0row + r][wv * 2] = p2;
                }
        }
        __syncthreads();   // sync_E1
        {
            f32x4 sh[4], sc[4];
#pragma unroll
            for (int r = 0; r < 4; ++r) {
                sh[r] = *(const f32x4*)(shb + r * 4);
                sc[r] = *(const f32x4*)(scb + r * 4);
            }
            float mean_[4], rstd_[4];
#pragma unroll
            for (int r = 0; r < 4; ++r) {
                f32x4 lo = *(const f32x4*)&part2[i0row + r][0];
                f32x4 hi = *(const f32x4*)&part2[i0row + r][4];
                float s  = (lo[0] + lo[2]) + (hi[0] + hi[2]);
                float ss = (lo[1] + lo[3]) + (hi[1] + hi[3]);
                mean_[r] = s * (1.f / 256.f);
                float var = ss * (1.f / 256.f) - mean_[r] * mean_[r];
                rstd_[r] = rsqrtf(var + 1e-5f);
            }
#pragma unroll
            for (int tn = 0; tn < 4; ++tn) {
                int colg = wv * 64 + tn * 16 + cl;
#pragma unroll
                for (int r = 0; r < 4; ++r) {
                    float nv = (tv[tn][r] - mean_[r]) * rstd_[r];
                    float hv = fmaf(sh[r][tn], nv, sc[r][tn]);
                    *(unsigned short*)(scr_raw + hswz(i0row + r, colg)) = f2bf(fmaxf(hv, 0.f));
                }
            }
        }
        __syncthreads();   // sync_E2: hsb + Wof-half0 ready

        // ======== GEMM3: y = hsb @ W_out, two staged 64 KB halves ===========
        f32x4 acc3[4];
#pragma unroll
        for (int tn = 0; tn < 4; ++tn) acc3[tn] = (f32x4){0.f, 0.f, 0.f, 0.f};
#pragma unroll
        for (int tkh = 0; tkh < 4; ++tkh) {
            short8 av = *(const short8*)(scr_raw + hswz(ig * 16 + cl, tkh * 32 + lhi * 8));
#pragma unroll
            for (int tn = 0; tn < 4; ++tn) {
                short8 bbv = *(const short8*)(wf_lds + (((wv * 4 + tn) * 4 + tkh) * 64 + lane) * 8);
                acc3[tn] = __builtin_amdgcn_mfma_f32_16x16x32_bf16(av, bbv, acc3[tn], 0, 0, 0);
            }
        }
        __syncthreads();                    // S_w: retire half0 reads
        stage_wof(Wof, 1, wf_lds, w, lane);
        __syncthreads();                    // S_w2: publish half1
#pragma unroll
        for (int tkh = 0; tkh < 4; ++tkh) {
            short8 av = *(const short8*)(scr_raw + hswz(ig * 16 + cl, (4 + tkh) * 32 + lhi * 8));
#pragma unroll
            for (int tn = 0; tn < 4; ++tn) {
                short8 bbv = *(const short8*)(wf_lds + (((wv * 4 + tn) * 4 + tkh) * 64 + lane) * 8);
                acc3[tn] = __builtin_amdgcn_mfma_f32_16x16x32_bf16(av, bbv, acc3[tn], 0, 0, 0);
            }
        }

        // ======== epilogue 2: tanh + mask -> h (LDS) [+ fp32 out last iter] ==
        const bool maskz = (64 - it) > len_b;
#pragma unroll
        for (int tn = 0; tn < 4; ++tn) {
            int colg = wv * 64 + tn * 16 + cl;
#pragma unroll
            for (int r = 0; r < 4; ++r) {
                float y = ftanh(acc3[tn][r] + bov[tn]);
                float ym = maskz ? 0.f : y;
                *(unsigned short*)(h_raw + hswz(i0row + r, colg)) = f2bf(ym);
                if (it == 63) h_out[(rowg0 + r) * DD + colg] = ym;
            }
        }
        __syncthreads();   // sync_E3: h ready; wf reads retired
        if (it < 63) stage_wf(Wf, 0, 0, wf_lds, w, lane);   // next iter chunk0/tp0
    } // it
}

// ---------------- final: out[b,d] = sum_i h[b,i,d] * root[b,i] ----------------
__global__ __launch_bounds__(256) void k_final(
    const float* __restrict__ h_buf, const float* __restrict__ root,
    float* __restrict__ out)
{
    const int t = threadIdx.x;
    const int b = blockIdx.x;
    float acc = 0.f;
    for (int i = 0; i < LLEN; ++i)
        acc = fmaf(h_buf[(b * 64 + i) * DD + t], root[b * 64 + i], acc);
    out[b * DD + t] = acc;
}

extern "C" void kernel_launch(void* const* d_in, const int* in_sizes, int n_in,
                              void* d_out, int out_size, void* d_ws, size_t ws_size,
                              hipStream_t stream)
{
    const int*   tokens = (const int*)  d_in[0];
    const float* A      = (const float*)d_in[1];
    const float* root   = (const float*)d_in[2];
    const float* emb    = (const float*)d_in[3];
    const float* Wp     = (const float*)d_in[4];
    const float* bp     = (const float*)d_in[5];
    const float* Wi     = (const float*)d_in[6];
    const float* bi     = (const float*)d_in[7];
    const float* Wo     = (const float*)d_in[8];
    const float* bo     = (const float*)d_in[9];
    float* out = (float*)d_out;

    char* ws = (char*)d_ws;
    int*   lengths = (int*)(ws + 0);
    float* shift2  = (float*)(ws + 1024);
    float* scale2  = shift2 + NROWS * DD;
    float* projx2  = scale2 + NROWS * DD;
    float* h_out   = projx2 + NROWS * DD;                          // 1 MB fp32
    unsigned short* Wf  = (unsigned short*)(h_out + NROWS * DD);   // 1 MB
    unsigned short* Af  = Wf + 524288;                             // 1 MB
    unsigned short* Wof = Af + 524288;                             // 128 KB

    k_prep<<<929, 256, 0, stream>>>(tokens, A, emb, Wp, Wi, bi, Wo,
                                    Wf, Af, Wof, shift2, scale2, projx2, lengths);
    k_loop<<<16, 1024, 0, stream>>>(Af, projx2, shift2, scale2, Wf, bp,
                                    Wof, bo, lengths, h_out);
    k_final<<<16, 256, 0, stream>>>(h_out, root, out);
}